// Round 2
// baseline (655.080 us; speedup 1.0000x reference)
//
#include <hip/hip_runtime.h>
#include <math.h>

#define NB 32
#define NN 4096      // 64*64
#define NNN 262144   // 64^3
#define PERMI(i) ((((i)&7)<<3)|((i)>>3))

__device__ __forceinline__ float2 cadd(float2 a, float2 b){ return make_float2(a.x+b.x, a.y+b.y); }
__device__ __forceinline__ float2 csub(float2 a, float2 b){ return make_float2(a.x-b.x, a.y-b.y); }
__device__ __forceinline__ float2 cmulc(float2 a, float2 b){ return make_float2(a.x*b.x - a.y*b.y, a.x*b.y + a.y*b.x); }
template<int S> __device__ __forceinline__ float2 cmuli(float2 a){
  return (S>0)? make_float2(-a.y,a.x) : make_float2(a.y,-a.x);
}

// 8-point DFT, natural order in/out. S=-1 forward, S=+1 inverse (unnormalized).
template<int S>
__device__ __forceinline__ void dft8(float2* a){
  const float r_ = 0.70710678118654752f;
  float2 t0=cadd(a[0],a[4]), t1=csub(a[0],a[4]);
  float2 t2=cadd(a[2],a[6]), t3=csub(a[2],a[6]);
  float2 u0=cadd(a[1],a[5]), u1=csub(a[1],a[5]);
  float2 u2=cadd(a[3],a[7]), u3=csub(a[3],a[7]);
  float2 E0=cadd(t0,t2), E2=csub(t0,t2);
  float2 it3=cmuli<S>(t3);
  float2 E1=cadd(t1,it3), E3=csub(t1,it3);
  float2 O0=cadd(u0,u2), O2=csub(u0,u2);
  float2 iu3=cmuli<S>(u3);
  float2 O1=cadd(u1,iu3), O3=csub(u1,iu3);
  const float sr = (S>0)? r_ : -r_;
  float2 W1 = make_float2(r_, sr);
  float2 W3 = make_float2(-r_, sr);
  float2 o1 = cmulc(O1,W1);
  float2 o2 = cmuli<S>(O2);
  float2 o3 = cmulc(O3,W3);
  a[0]=cadd(E0,O0); a[4]=csub(E0,O0);
  a[1]=cadd(E1,o1); a[5]=csub(E1,o1);
  a[2]=cadd(E2,o2); a[6]=csub(E2,o2);
  a[3]=cadd(E3,o3); a[7]=csub(E3,o3);
}

#define TWTAB \
  const float TWC[8]={1.f,0.9951847266721969f,0.9807852804032304f,0.9569403357322088f, \
                      0.9238795325112867f,0.8819212643483551f,0.8314696123025452f,0.7730104533627370f}; \
  const float TWS[8]={0.f,0.0980171403295606f,0.1950903220161283f,0.2902846772544624f, \
                      0.3826834323650898f,0.4713967368259976f,0.5555702330196022f,0.6343932841636455f};

// 64-pt DFT radix-8x8, natural input, output logical i at v[PERMI(i)]. In-place safe.
template<int S>
__device__ __forceinline__ void fft64(float2* v){
  #pragma unroll
  for(int n2=0;n2<8;n2++){            // column DFTs (stride-8 reads), in-place per column
    float2 t[8];
    #pragma unroll
    for(int n1=0;n1<8;n1++) t[n1] = v[8*n1+n2];
    dft8<S>(t);
    #pragma unroll
    for(int k1=0;k1<8;k1++) v[8*k1+n2] = t[k1];
  }
  TWTAB
  #pragma unroll
  for(int k1=1;k1<8;k1++){
    float2 wb = make_float2(TWC[k1], (S>0)? TWS[k1] : -TWS[k1]);
    float2 w = wb;
    #pragma unroll
    for(int n2=1;n2<8;n2++){
      v[8*k1+n2] = cmulc(v[8*k1+n2], w);
      w = cmulc(w, wb);
    }
  }
  #pragma unroll
  for(int k1=0;k1<8;k1++){            // row DFTs, in-place
    float2 t[8];
    #pragma unroll
    for(int n2=0;n2<8;n2++) t[n2]=v[8*k1+n2];
    dft8<S>(t);
    #pragma unroll
    for(int k2=0;k2<8;k2++) v[8*k1+k2]=t[k2];
  }
}

// 64-pt DFT, input logical i at v[PERMI(i)] (transpose placement), output NATURAL
// order in place. Derivation: M[b][a]=x[8a+b]; row-DFTs; symmetric twiddle W^{b*q};
// column-DFTs -> y[8m+q] at M[m][q]=v[8m+q].
template<int S>
__device__ __forceinline__ void fft64_pin_nat(float2* v){
  #pragma unroll
  for(int r=0;r<8;r++){               // row DFTs (contiguous 8), in-place
    float2 t[8];
    #pragma unroll
    for(int a=0;a<8;a++) t[a]=v[8*r+a];
    dft8<S>(t);
    #pragma unroll
    for(int q=0;q<8;q++) v[8*r+q]=t[q];
  }
  TWTAB
  #pragma unroll
  for(int r=1;r<8;r++){               // twiddle W^{r*q}
    float2 wb = make_float2(TWC[r], (S>0)? TWS[r] : -TWS[r]);
    float2 w = wb;
    #pragma unroll
    for(int q=1;q<8;q++){
      v[8*r+q] = cmulc(v[8*r+q], w);
      w = cmulc(w, wb);
    }
  }
  #pragma unroll
  for(int q=0;q<8;q++){               // column DFTs, in-place per column
    float2 t[8];
    #pragma unroll
    for(int b=0;b<8;b++) t[b]=v[8*b+q];
    dft8<S>(t);
    #pragma unroll
    for(int m=0;m<8;m++) v[8*m+q]=t[m];
  }
}

// ---------------- affine params ----------------
__global__ void k_affine(const float* __restrict__ theta, float* __restrict__ aff){
  int b = threadIdx.x;
  if(b >= NB) return;
  const float* t = theta + b*6;
  const float PIf = 3.14159265358979323846f;
  float phi = t[0]*(2.f*PIf) - PIf;
  float th  = t[1]*(2.f*PIf) - PIf;
  float psi = t[2]*(2.f*PIf) - PIf;
  float cph = cosf(phi), sph = sinf(phi);
  float cth = cosf(th),  sth = sinf(th);
  float cps = cosf(psi), sps = sinf(psi);
  float R00 = cph*cth*cps - sph*sps;
  float R01 = -cph*cth*sps - sph*cps;
  float R02 = cph*sth;
  float R10 = sph*cth*cps + cph*sps;
  float R11 = -sph*cth*sps + cph*cps;
  float R12 = sph*sth;
  float R20 = -sth*cps;
  float R21 = sth*sps;
  float R22 = cth;
  float rm0=R00, rm1=R10, rm2=R20;
  float rm3=R01, rm4=R11, rm5=R21;
  float rm6=R02, rm7=R12, rm8=R22;
  float* o = aff + b*16;
  o[0]=rm0; o[1]=rm1; o[2]=rm2;
  o[3]=rm3; o[4]=rm4; o[5]=rm5;
  o[6]=rm6; o[7]=rm7; o[8]=rm8;
  const float sc = 64.0f/66.0f;
  float lx = (2.f*t[3]-1.f)*sc;
  float ly = (2.f*t[4]-1.f)*sc;
  float lz = (2.f*t[5]-1.f)*sc;
  o[9]  = -(rm0*lx + rm1*ly + rm2*lz);
  o[10] = -(rm3*lx + rm4*ly + rm5*lz);
  o[11] = -(rm6*lx + rm7*ly + rm8*lz);
}

// block/tile decode with XCD pinning: blk&7 = XCD slot; each batch's 512 tile-blocks
// stay on one XCD so its 2MB mask footprint is L2-resident.
__device__ __forceinline__ void tile_decode(int blk, int& batch, int& ox, int& oy, int& oz){
  int xcd = blk & 7;
  int j = blk >> 3;                 // 0..2047
  batch = xcd + ((j >> 9) << 3);    // 4 batches per XCD slot
  int tile = j & 511;
  oz = (tile & 7) << 3;
  oy = ((tile >> 3) & 7) << 3;
  ox = (tile >> 6) << 3;
}

#define LDSI(xi,yi,zi) ((((xi)*16)+(yi))*17+(zi))

// ---------------- mask warp: LDS-staged tiled gather ----------------
__global__ __launch_bounds__(256) void k_warp_masks(const float* __restrict__ m1, const float* __restrict__ m2,
                             const float* __restrict__ aff,
                             float* __restrict__ M1, float* __restrict__ M2){
  __shared__ float s1[16*16*17];
  __shared__ float s2[16*16*17];
  int batch, ox, oy, oz;
  tile_decode(blockIdx.x, batch, ox, oy, oz);
  const float* a = aff + batch*16;
  float a0=a[0],a1=a[1],a2=a[2],a3=a[3],a4=a[4],a5=a[5],a6=a[6],a7=a[7],a8=a[8];

  // analytic bbox of rotated tile (+halo), extent provably < 16
  float gxl = ox*(2.f/63.f)-1.f, gxh = (ox+7)*(2.f/63.f)-1.f;
  float gyl = oy*(2.f/63.f)-1.f, gyh = (oy+7)*(2.f/63.f)-1.f;
  float gzl = oz*(2.f/63.f)-1.f, gzh = (oz+7)*(2.f/63.f)-1.f;
  #define MM(c,lo,hi) fminf((c)*(lo),(c)*(hi))
  float minx = (1.f + MM(a0,gxl,gxh) + MM(a1,gyl,gyh) + MM(a2,gzl,gzh))*31.5f;
  float miny = (1.f + MM(a3,gxl,gxh) + MM(a4,gyl,gyh) + MM(a5,gzl,gzh))*31.5f;
  float minz = (1.f + MM(a6,gxl,gxh) + MM(a7,gyl,gyh) + MM(a8,gzl,gzh))*31.5f;
  #undef MM
  int sx0 = min(max((int)floorf(minx-0.01f),0),48);
  int sy0 = min(max((int)floorf(miny-0.01f),0),48);
  int sz0 = min(max((int)floorf(minz-0.01f),0),48);

  // stage 16^3 window (coords sx0+[0,16) always within [0,63])
  {
    int zi = threadIdx.x & 15, yi = threadIdx.x >> 4;
    const float* p1 = m1 + (size_t)batch*NNN + ((sy0+yi)<<6) + (sz0+zi);
    const float* p2 = m2 + (size_t)batch*NNN + ((sy0+yi)<<6) + (sz0+zi);
    #pragma unroll
    for(int xi=0;xi<16;xi++){
      s1[LDSI(xi,yi,zi)] = p1[(size_t)(sx0+xi)<<12];
      s2[LDSI(xi,yi,zi)] = p2[(size_t)(sx0+xi)<<12];
    }
  }
  __syncthreads();

  #pragma unroll
  for(int o=0;o<2;o++){
    int v = threadIdx.x + o*256;
    int zo = v & 7, yo = (v>>3)&7, xo = v>>6;
    float gx = (ox+xo)*(2.f/63.f)-1.f;
    float gy = (oy+yo)*(2.f/63.f)-1.f;
    float gz = (oz+zo)*(2.f/63.f)-1.f;
    float px = (a0*gx + a1*gy + a2*gz + 1.f)*31.5f;
    float py = (a3*gx + a4*gy + a5*gz + 1.f)*31.5f;
    float pz = (a6*gx + a7*gy + a8*gz + 1.f)*31.5f;
    int xf=(int)floorf(px), yf=(int)floorf(py), zf=(int)floorf(pz);
    int x0=min(max(xf,0),63), x1=min(max(xf+1,0),63);
    int y0=min(max(yf,0),63), y1=min(max(yf+1,0),63);
    int z0=min(max(zf,0),63), z1=min(max(zf+1,0),63);
    float dx=px-(float)x0, dy=py-(float)y0, dz=pz-(float)z0;
    float ex=1.f-dx, ey=1.f-dy, ez=1.f-dz;
    int lx0=min(max(x0-sx0,0),15), lx1=min(max(x1-sx0,0),15);
    int ly0=min(max(y0-sy0,0),15), ly1=min(max(y1-sy0,0),15);
    int lz0=min(max(z0-sz0,0),15), lz1=min(max(z1-sz0,0),15);
    int xA=lx0*272, xB=lx1*272, yA=ly0*17, yB=ly1*17;
    int i000=xA+yA+lz0, i001=xA+yA+lz1, i010=xA+yB+lz0, i011=xA+yB+lz1;
    int i100=xB+yA+lz0, i101=xB+yA+lz1, i110=xB+yB+lz0, i111=xB+yB+lz1;
    float w000=ex*ey*ez, w001=ex*ey*dz, w010=ex*dy*ez, w011=ex*dy*dz;
    float w100=dx*ey*ez, w101=dx*ey*dz, w110=dx*dy*ez, w111=dx*dy*dz;
    float r1 = w000*s1[i000]+w001*s1[i001]+w010*s1[i010]+w011*s1[i011]
             + w100*s1[i100]+w101*s1[i101]+w110*s1[i110]+w111*s1[i111];
    float r2 = w000*s2[i000]+w001*s2[i001]+w010*s2[i010]+w011*s2[i011]
             + w100*s2[i100]+w101*s2[i101]+w110*s2[i110]+w111*s2[i111];
    size_t oi = (size_t)batch*NNN + ((size_t)(ox+xo)<<12) + ((oy+yo)<<6) + (oz+zo);
    M1[oi] = r1;
    M2[oi] = r2;
  }
}

// ---------------- X warp: LDS-staged tiled gather over padded-66 space -------
__global__ __launch_bounds__(256) void k_warp_x(const float* __restrict__ X, const float* __restrict__ aff,
                         float* __restrict__ Xt){
  __shared__ float sX[16*16*17];
  int batch, ox, oy, oz;
  tile_decode(blockIdx.x, batch, ox, oy, oz);
  const float* a = aff + batch*16;
  float a0=a[0],a1=a[1],a2=a[2],a3=a[3],a4=a[4],a5=a[5],a6=a[6],a7=a[7],a8=a[8];
  float c0=a[9], c1=a[10], c2=a[11];

  // padded grid: g = (idx+1)*(2/65)-1, p = (t+1)*32.5, idx range [0,65]
  float gxl = (ox+1)*(2.f/65.f)-1.f, gxh = (ox+8)*(2.f/65.f)-1.f;
  float gyl = (oy+1)*(2.f/65.f)-1.f, gyh = (oy+8)*(2.f/65.f)-1.f;
  float gzl = (oz+1)*(2.f/65.f)-1.f, gzh = (oz+8)*(2.f/65.f)-1.f;
  #define MM(c,lo,hi) fminf((c)*(lo),(c)*(hi))
  float minx = (MM(a0,gxl,gxh) + MM(a1,gyl,gyh) + MM(a2,gzl,gzh) + c0 + 1.f)*32.5f;
  float miny = (MM(a3,gxl,gxh) + MM(a4,gyl,gyh) + MM(a5,gzl,gzh) + c1 + 1.f)*32.5f;
  float minz = (MM(a6,gxl,gxh) + MM(a7,gyl,gyh) + MM(a8,gzl,gzh) + c2 + 1.f)*32.5f;
  #undef MM
  int sx0 = min(max((int)floorf(minx-0.01f),0),50);
  int sy0 = min(max((int)floorf(miny-0.01f),0),50);
  int sz0 = min(max((int)floorf(minz-0.01f),0),50);

  // stage 16^3 window of padded space: coord c in [0,65]; interior [1,64] -> X[c-1], else 0
  {
    int zi = threadIdx.x & 15, yi = threadIdx.x >> 4;
    int ys = sy0 + yi, zs = sz0 + zi;
    bool yz_ok = ((unsigned)(ys-1) < 64u) && ((unsigned)(zs-1) < 64u);
    const float* p = X + (size_t)batch*NNN + ((ys-1)<<6) + (zs-1);
    #pragma unroll
    for(int xi=0;xi<16;xi++){
      int xs = sx0 + xi;
      float val = (yz_ok && ((unsigned)(xs-1) < 64u)) ? p[(size_t)(xs-1)<<12] : 0.f;
      sX[LDSI(xi,yi,zi)] = val;
    }
  }
  __syncthreads();

  #pragma unroll
  for(int o=0;o<2;o++){
    int v = threadIdx.x + o*256;
    int zo = v & 7, yo = (v>>3)&7, xo = v>>6;
    float gx = (ox+xo+1)*(2.f/65.f)-1.f;
    float gy = (oy+yo+1)*(2.f/65.f)-1.f;
    float gz = (oz+zo+1)*(2.f/65.f)-1.f;
    float px = (a0*gx + a1*gy + a2*gz + c0 + 1.f)*32.5f;
    float py = (a3*gx + a4*gy + a5*gz + c1 + 1.f)*32.5f;
    float pz = (a6*gx + a7*gy + a8*gz + c2 + 1.f)*32.5f;
    int xf=(int)floorf(px), yf=(int)floorf(py), zf=(int)floorf(pz);
    int x0=min(max(xf,0),65), x1=min(max(xf+1,0),65);
    int y0=min(max(yf,0),65), y1=min(max(yf+1,0),65);
    int z0=min(max(zf,0),65), z1=min(max(zf+1,0),65);
    float dx=px-(float)x0, dy=py-(float)y0, dz=pz-(float)z0;
    float ex=1.f-dx, ey=1.f-dy, ez=1.f-dz;
    int lx0=min(max(x0-sx0,0),15), lx1=min(max(x1-sx0,0),15);
    int ly0=min(max(y0-sy0,0),15), ly1=min(max(y1-sy0,0),15);
    int lz0=min(max(z0-sz0,0),15), lz1=min(max(z1-sz0,0),15);
    int xA=lx0*272, xB=lx1*272, yA=ly0*17, yB=ly1*17;
    float rv = ex*ey*ez*sX[xA+yA+lz0] + ex*ey*dz*sX[xA+yA+lz1]
             + ex*dy*ez*sX[xA+yB+lz0] + ex*dy*dz*sX[xA+yB+lz1]
             + dx*ey*ez*sX[xB+yA+lz0] + dx*ey*dz*sX[xB+yA+lz1]
             + dx*dy*ez*sX[xB+yB+lz0] + dx*dy*dz*sX[xB+yB+lz1];
    size_t oi = (size_t)batch*NNN + ((size_t)(ox+xo)<<12) + ((oy+yo)<<6) + (oz+zo);
    Xt[oi] = rv;
  }
}

// ---------------- forward slab: FFT over y then z for one (b,x) slab --------
__global__ __launch_bounds__(64,1) void k_fwd_slab(const float* __restrict__ src, float2* __restrict__ dst){
  __shared__ float re[64*65];
  __shared__ float im[64*65];
  int s = blockIdx.x;
  int t = threadIdx.x;
  const float* p = src + (size_t)s*NN;
  float2 v[64];
  #pragma unroll
  for(int y=0;y<64;y++) v[y] = make_float2(p[y*64+t], 0.f);
  fft64<-1>(v);
  #pragma unroll
  for(int i=0;i<64;i++){ float2 q = v[PERMI(i)]; re[i*65+t]=q.x; im[i*65+t]=q.y; }
  __syncthreads();
  #pragma unroll
  for(int z=0;z<64;z++) v[z] = make_float2(re[t*65+z], im[t*65+z]);
  fft64<-1>(v);
  #pragma unroll
  for(int i=0;i<64;i++){ float2 q = v[PERMI(i)]; re[t*65+i]=q.x; im[t*65+i]=q.y; }
  __syncthreads();
  float2* d = dst + (size_t)s*NN;
  #pragma unroll
  for(int i=0;i<64;i++) d[i*64+t] = make_float2(re[i*65+t], im[i*65+t]);
}

// ------- conv along x: FFT-x, multiply by shifted mask, iFFT-x, in place ----
__global__ __launch_bounds__(256,2) void k_conv_x(float2* __restrict__ A, const float* __restrict__ M){
  int lid = blockIdx.x*blockDim.x + threadIdx.x;
  int z = lid & 63, y = (lid>>6) & 63, b = lid>>12;
  float2* p = A + (size_t)b*NNN + y*64 + z;
  const float* m = M + (size_t)b*NNN + ((y^32)<<6) + (z^32);
  float2 v[64];
  #pragma unroll
  for(int k=0;k<64;k++) v[k] = p[(size_t)k*NN];
  fft64<-1>(v);
  #pragma unroll
  for(int i=0;i<64;i++){
    float mm = m[(size_t)(i^32)*NN];
    v[PERMI(i)].x *= mm;
    v[PERMI(i)].y *= mm;
  }
  fft64_pin_nat<1>(v);     // PERM-placed input -> natural output, in place
  #pragma unroll
  for(int i=0;i<64;i++) p[(size_t)i*NN] = v[i];
}

// -------- inverse slab: iFFT over y then z, scale, take real, write/acc -----
template<bool ACC>
__global__ __launch_bounds__(64,1) void k_inv_slab(const float2* __restrict__ src, float* __restrict__ dst){
  __shared__ float re[64*65];
  __shared__ float im[64*65];
  int s = blockIdx.x;
  int t = threadIdx.x;
  const float2* p = src + (size_t)s*NN;
  float2 v[64];
  #pragma unroll
  for(int ky=0;ky<64;ky++) v[ky] = p[ky*64+t];
  fft64<1>(v);
  #pragma unroll
  for(int i=0;i<64;i++){ float2 q = v[PERMI(i)]; re[i*65+t]=q.x; im[i*65+t]=q.y; }
  __syncthreads();
  #pragma unroll
  for(int kz=0;kz<64;kz++) v[kz] = make_float2(re[t*65+kz], im[t*65+kz]);
  fft64<1>(v);
  const float scl = 1.0f/262144.0f;
  #pragma unroll
  for(int i=0;i<64;i++) re[t*65+i] = v[PERMI(i)].x * scl;
  __syncthreads();
  float* d = dst + (size_t)s*NN;
  #pragma unroll
  for(int i=0;i<64;i++){
    float val = re[i*65+t];
    if (ACC) d[i*64+t] += val; else d[i*64+t] = val;
  }
}

extern "C" void kernel_launch(void* const* d_in, const int* in_sizes, int n_in,
                              void* d_out, int out_size, void* d_ws, size_t ws_size,
                              hipStream_t stream){
  const float* X  = (const float*)d_in[0];
  const float* Y  = (const float*)d_in[1];
  const float* m1 = (const float*)d_in[2];
  const float* m2 = (const float*)d_in[3];
  const float* th = (const float*)d_in[4];
  float* out0 = (float*)d_out;
  float* out1 = out0 + (size_t)NB*NNN;
  float* out2 = out1 + (size_t)NB*NNN;
  float2* A  = (float2*)d_ws;
  float*  aff = (float*)((char*)d_ws + (size_t)NB*NNN*sizeof(float2));

  k_affine<<<dim3(1), dim3(32), 0, stream>>>(th, aff);
  k_warp_masks<<<dim3(NB*512), dim3(256), 0, stream>>>(m1, m2, aff, out1, out2);
  k_warp_x<<<dim3(NB*512), dim3(256), 0, stream>>>(X, aff, out0);

  k_fwd_slab<<<dim3(NB*64), dim3(64), 0, stream>>>(out0, A);
  k_conv_x<<<dim3(NB*NN/256), dim3(256), 0, stream>>>(A, out1);
  k_inv_slab<false><<<dim3(NB*64), dim3(64), 0, stream>>>(A, out0);

  k_fwd_slab<<<dim3(NB*64), dim3(64), 0, stream>>>(Y, A);
  k_conv_x<<<dim3(NB*NN/256), dim3(256), 0, stream>>>(A, out2);
  k_inv_slab<true><<<dim3(NB*64), dim3(64), 0, stream>>>(A, out0);
}

// Round 3
// 468.342 us; speedup vs baseline: 1.3987x; 1.3987x over previous
//
#include <hip/hip_runtime.h>
#include <math.h>

#define NB 32
#define NN 4096      // 64*64
#define NNN 262144   // 64^3
#define PERMI(i) ((((i)&7)<<3)|((i)>>3))

__device__ __forceinline__ float2 cadd(float2 a, float2 b){ return make_float2(a.x+b.x, a.y+b.y); }
__device__ __forceinline__ float2 csub(float2 a, float2 b){ return make_float2(a.x-b.x, a.y-b.y); }
__device__ __forceinline__ float2 cmulc(float2 a, float2 b){ return make_float2(a.x*b.x - a.y*b.y, a.x*b.y + a.y*b.x); }
template<int S> __device__ __forceinline__ float2 cmuli(float2 a){
  return (S>0)? make_float2(-a.y,a.x) : make_float2(a.y,-a.x);
}

// 8-point DFT, natural order in/out. S=-1 forward, S=+1 inverse (unnormalized).
template<int S>
__device__ __forceinline__ void dft8(float2* a){
  const float r_ = 0.70710678118654752f;
  float2 t0=cadd(a[0],a[4]), t1=csub(a[0],a[4]);
  float2 t2=cadd(a[2],a[6]), t3=csub(a[2],a[6]);
  float2 u0=cadd(a[1],a[5]), u1=csub(a[1],a[5]);
  float2 u2=cadd(a[3],a[7]), u3=csub(a[3],a[7]);
  float2 E0=cadd(t0,t2), E2=csub(t0,t2);
  float2 it3=cmuli<S>(t3);
  float2 E1=cadd(t1,it3), E3=csub(t1,it3);
  float2 O0=cadd(u0,u2), O2=csub(u0,u2);
  float2 iu3=cmuli<S>(u3);
  float2 O1=cadd(u1,iu3), O3=csub(u1,iu3);
  const float sr = (S>0)? r_ : -r_;
  float2 W1 = make_float2(r_, sr);
  float2 W3 = make_float2(-r_, sr);
  float2 o1 = cmulc(O1,W1);
  float2 o2 = cmuli<S>(O2);
  float2 o3 = cmulc(O3,W3);
  a[0]=cadd(E0,O0); a[4]=csub(E0,O0);
  a[1]=cadd(E1,o1); a[5]=csub(E1,o1);
  a[2]=cadd(E2,o2); a[6]=csub(E2,o2);
  a[3]=cadd(E3,o3); a[7]=csub(E3,o3);
}

#define TWTAB \
  const float TWC[8]={1.f,0.9951847266721969f,0.9807852804032304f,0.9569403357322088f, \
                      0.9238795325112867f,0.8819212643483551f,0.8314696123025452f,0.7730104533627370f}; \
  const float TWS[8]={0.f,0.0980171403295606f,0.1950903220161283f,0.2902846772544624f, \
                      0.3826834323650898f,0.4713967368259976f,0.5555702330196022f,0.6343932841636455f};

// 64-pt DFT radix-8x8, natural input, output logical i at v[PERMI(i)]. In-place safe.
template<int S>
__device__ __forceinline__ void fft64(float2* v){
  #pragma unroll
  for(int n2=0;n2<8;n2++){            // column DFTs (stride-8 reads), in-place per column
    float2 t[8];
    #pragma unroll
    for(int n1=0;n1<8;n1++) t[n1] = v[8*n1+n2];
    dft8<S>(t);
    #pragma unroll
    for(int k1=0;k1<8;k1++) v[8*k1+n2] = t[k1];
  }
  TWTAB
  #pragma unroll
  for(int k1=1;k1<8;k1++){
    float2 wb = make_float2(TWC[k1], (S>0)? TWS[k1] : -TWS[k1]);
    float2 w = wb;
    #pragma unroll
    for(int n2=1;n2<8;n2++){
      v[8*k1+n2] = cmulc(v[8*k1+n2], w);
      w = cmulc(w, wb);
    }
  }
  #pragma unroll
  for(int k1=0;k1<8;k1++){            // row DFTs, in-place
    float2 t[8];
    #pragma unroll
    for(int n2=0;n2<8;n2++) t[n2]=v[8*k1+n2];
    dft8<S>(t);
    #pragma unroll
    for(int k2=0;k2<8;k2++) v[8*k1+k2]=t[k2];
  }
}

// 64-pt DFT, input logical i at v[PERMI(i)] (transpose placement), output NATURAL
// order in place.
template<int S>
__device__ __forceinline__ void fft64_pin_nat(float2* v){
  #pragma unroll
  for(int r=0;r<8;r++){               // row DFTs (contiguous 8), in-place
    float2 t[8];
    #pragma unroll
    for(int a=0;a<8;a++) t[a]=v[8*r+a];
    dft8<S>(t);
    #pragma unroll
    for(int q=0;q<8;q++) v[8*r+q]=t[q];
  }
  TWTAB
  #pragma unroll
  for(int r=1;r<8;r++){               // twiddle W^{r*q}
    float2 wb = make_float2(TWC[r], (S>0)? TWS[r] : -TWS[r]);
    float2 w = wb;
    #pragma unroll
    for(int q=1;q<8;q++){
      v[8*r+q] = cmulc(v[8*r+q], w);
      w = cmulc(w, wb);
    }
  }
  #pragma unroll
  for(int q=0;q<8;q++){               // column DFTs, in-place per column
    float2 t[8];
    #pragma unroll
    for(int b=0;b<8;b++) t[b]=v[8*b+q];
    dft8<S>(t);
    #pragma unroll
    for(int m=0;m<8;m++) v[8*m+q]=t[m];
  }
}

// ---------------- affine params ----------------
__global__ void k_affine(const float* __restrict__ theta, float* __restrict__ aff){
  int b = threadIdx.x;
  if(b >= NB) return;
  const float* t = theta + b*6;
  const float PIf = 3.14159265358979323846f;
  float phi = t[0]*(2.f*PIf) - PIf;
  float th  = t[1]*(2.f*PIf) - PIf;
  float psi = t[2]*(2.f*PIf) - PIf;
  float cph = cosf(phi), sph = sinf(phi);
  float cth = cosf(th),  sth = sinf(th);
  float cps = cosf(psi), sps = sinf(psi);
  float R00 = cph*cth*cps - sph*sps;
  float R01 = -cph*cth*sps - sph*cps;
  float R02 = cph*sth;
  float R10 = sph*cth*cps + cph*sps;
  float R11 = -sph*cth*sps + cph*cps;
  float R12 = sph*sth;
  float R20 = -sth*cps;
  float R21 = sth*sps;
  float R22 = cth;
  float rm0=R00, rm1=R10, rm2=R20;
  float rm3=R01, rm4=R11, rm5=R21;
  float rm6=R02, rm7=R12, rm8=R22;
  float* o = aff + b*16;
  o[0]=rm0; o[1]=rm1; o[2]=rm2;
  o[3]=rm3; o[4]=rm4; o[5]=rm5;
  o[6]=rm6; o[7]=rm7; o[8]=rm8;
  const float sc = 64.0f/66.0f;
  float lx = (2.f*t[3]-1.f)*sc;
  float ly = (2.f*t[4]-1.f)*sc;
  float lz = (2.f*t[5]-1.f)*sc;
  o[9]  = -(rm0*lx + rm1*ly + rm2*lz);
  o[10] = -(rm3*lx + rm4*ly + rm5*lz);
  o[11] = -(rm6*lx + rm7*ly + rm8*lz);
}

// block/tile decode with XCD pinning
__device__ __forceinline__ void tile_decode(int blk, int& batch, int& ox, int& oy, int& oz){
  int xcd = blk & 7;
  int j = blk >> 3;
  batch = xcd + ((j >> 9) << 3);
  int tile = j & 511;
  oz = (tile & 7) << 3;
  oy = ((tile >> 3) & 7) << 3;
  ox = (tile >> 6) << 3;
}

#define LDSI(xi,yi,zi) ((((xi)*16)+(yi))*17+(zi))

// ---------------- mask warp: LDS-staged tiled gather ----------------
__global__ __launch_bounds__(256) void k_warp_masks(const float* __restrict__ m1, const float* __restrict__ m2,
                             const float* __restrict__ aff,
                             float* __restrict__ M1, float* __restrict__ M2){
  __shared__ float s1[16*16*17];
  __shared__ float s2[16*16*17];
  int batch, ox, oy, oz;
  tile_decode(blockIdx.x, batch, ox, oy, oz);
  const float* a = aff + batch*16;
  float a0=a[0],a1=a[1],a2=a[2],a3=a[3],a4=a[4],a5=a[5],a6=a[6],a7=a[7],a8=a[8];

  float gxl = ox*(2.f/63.f)-1.f, gxh = (ox+7)*(2.f/63.f)-1.f;
  float gyl = oy*(2.f/63.f)-1.f, gyh = (oy+7)*(2.f/63.f)-1.f;
  float gzl = oz*(2.f/63.f)-1.f, gzh = (oz+7)*(2.f/63.f)-1.f;
  #define MM(c,lo,hi) fminf((c)*(lo),(c)*(hi))
  float minx = (1.f + MM(a0,gxl,gxh) + MM(a1,gyl,gyh) + MM(a2,gzl,gzh))*31.5f;
  float miny = (1.f + MM(a3,gxl,gxh) + MM(a4,gyl,gyh) + MM(a5,gzl,gzh))*31.5f;
  float minz = (1.f + MM(a6,gxl,gxh) + MM(a7,gyl,gyh) + MM(a8,gzl,gzh))*31.5f;
  #undef MM
  int sx0 = min(max((int)floorf(minx-0.01f),0),48);
  int sy0 = min(max((int)floorf(miny-0.01f),0),48);
  int sz0 = min(max((int)floorf(minz-0.01f),0),48);

  {
    int zi = threadIdx.x & 15, yi = threadIdx.x >> 4;
    const float* p1 = m1 + (size_t)batch*NNN + ((sy0+yi)<<6) + (sz0+zi);
    const float* p2 = m2 + (size_t)batch*NNN + ((sy0+yi)<<6) + (sz0+zi);
    #pragma unroll
    for(int xi=0;xi<16;xi++){
      s1[LDSI(xi,yi,zi)] = p1[(size_t)(sx0+xi)<<12];
      s2[LDSI(xi,yi,zi)] = p2[(size_t)(sx0+xi)<<12];
    }
  }
  __syncthreads();

  #pragma unroll
  for(int o=0;o<2;o++){
    int v = threadIdx.x + o*256;
    int zo = v & 7, yo = (v>>3)&7, xo = v>>6;
    float gx = (ox+xo)*(2.f/63.f)-1.f;
    float gy = (oy+yo)*(2.f/63.f)-1.f;
    float gz = (oz+zo)*(2.f/63.f)-1.f;
    float px = (a0*gx + a1*gy + a2*gz + 1.f)*31.5f;
    float py = (a3*gx + a4*gy + a5*gz + 1.f)*31.5f;
    float pz = (a6*gx + a7*gy + a8*gz + 1.f)*31.5f;
    int xf=(int)floorf(px), yf=(int)floorf(py), zf=(int)floorf(pz);
    int x0=min(max(xf,0),63), x1=min(max(xf+1,0),63);
    int y0=min(max(yf,0),63), y1=min(max(yf+1,0),63);
    int z0=min(max(zf,0),63), z1=min(max(zf+1,0),63);
    float dx=px-(float)x0, dy=py-(float)y0, dz=pz-(float)z0;
    float ex=1.f-dx, ey=1.f-dy, ez=1.f-dz;
    int lx0=min(max(x0-sx0,0),15), lx1=min(max(x1-sx0,0),15);
    int ly0=min(max(y0-sy0,0),15), ly1=min(max(y1-sy0,0),15);
    int lz0=min(max(z0-sz0,0),15), lz1=min(max(z1-sz0,0),15);
    int xA=lx0*272, xB=lx1*272, yA=ly0*17, yB=ly1*17;
    int i000=xA+yA+lz0, i001=xA+yA+lz1, i010=xA+yB+lz0, i011=xA+yB+lz1;
    int i100=xB+yA+lz0, i101=xB+yA+lz1, i110=xB+yB+lz0, i111=xB+yB+lz1;
    float w000=ex*ey*ez, w001=ex*ey*dz, w010=ex*dy*ez, w011=ex*dy*dz;
    float w100=dx*ey*ez, w101=dx*ey*dz, w110=dx*dy*ez, w111=dx*dy*dz;
    float r1 = w000*s1[i000]+w001*s1[i001]+w010*s1[i010]+w011*s1[i011]
             + w100*s1[i100]+w101*s1[i101]+w110*s1[i110]+w111*s1[i111];
    float r2 = w000*s2[i000]+w001*s2[i001]+w010*s2[i010]+w011*s2[i011]
             + w100*s2[i100]+w101*s2[i101]+w110*s2[i110]+w111*s2[i111];
    size_t oi = (size_t)batch*NNN + ((size_t)(ox+xo)<<12) + ((oy+yo)<<6) + (oz+zo);
    M1[oi] = r1;
    M2[oi] = r2;
  }
}

// ---------------- X warp: LDS-staged tiled gather over padded-66 space -------
__global__ __launch_bounds__(256) void k_warp_x(const float* __restrict__ X, const float* __restrict__ aff,
                         float* __restrict__ Xt){
  __shared__ float sX[16*16*17];
  int batch, ox, oy, oz;
  tile_decode(blockIdx.x, batch, ox, oy, oz);
  const float* a = aff + batch*16;
  float a0=a[0],a1=a[1],a2=a[2],a3=a[3],a4=a[4],a5=a[5],a6=a[6],a7=a[7],a8=a[8];
  float c0=a[9], c1=a[10], c2=a[11];

  float gxl = (ox+1)*(2.f/65.f)-1.f, gxh = (ox+8)*(2.f/65.f)-1.f;
  float gyl = (oy+1)*(2.f/65.f)-1.f, gyh = (oy+8)*(2.f/65.f)-1.f;
  float gzl = (oz+1)*(2.f/65.f)-1.f, gzh = (oz+8)*(2.f/65.f)-1.f;
  #define MM(c,lo,hi) fminf((c)*(lo),(c)*(hi))
  float minx = (MM(a0,gxl,gxh) + MM(a1,gyl,gyh) + MM(a2,gzl,gzh) + c0 + 1.f)*32.5f;
  float miny = (MM(a3,gxl,gxh) + MM(a4,gyl,gyh) + MM(a5,gzl,gzh) + c1 + 1.f)*32.5f;
  float minz = (MM(a6,gxl,gxh) + MM(a7,gyl,gyh) + MM(a8,gzl,gzh) + c2 + 1.f)*32.5f;
  #undef MM
  int sx0 = min(max((int)floorf(minx-0.01f),0),50);
  int sy0 = min(max((int)floorf(miny-0.01f),0),50);
  int sz0 = min(max((int)floorf(minz-0.01f),0),50);

  {
    int zi = threadIdx.x & 15, yi = threadIdx.x >> 4;
    int ys = sy0 + yi, zs = sz0 + zi;
    bool yz_ok = ((unsigned)(ys-1) < 64u) && ((unsigned)(zs-1) < 64u);
    const float* p = X + (size_t)batch*NNN + ((ys-1)<<6) + (zs-1);
    #pragma unroll
    for(int xi=0;xi<16;xi++){
      int xs = sx0 + xi;
      float val = (yz_ok && ((unsigned)(xs-1) < 64u)) ? p[(size_t)(xs-1)<<12] : 0.f;
      sX[LDSI(xi,yi,zi)] = val;
    }
  }
  __syncthreads();

  #pragma unroll
  for(int o=0;o<2;o++){
    int v = threadIdx.x + o*256;
    int zo = v & 7, yo = (v>>3)&7, xo = v>>6;
    float gx = (ox+xo+1)*(2.f/65.f)-1.f;
    float gy = (oy+yo+1)*(2.f/65.f)-1.f;
    float gz = (oz+zo+1)*(2.f/65.f)-1.f;
    float px = (a0*gx + a1*gy + a2*gz + c0 + 1.f)*32.5f;
    float py = (a3*gx + a4*gy + a5*gz + c1 + 1.f)*32.5f;
    float pz = (a6*gx + a7*gy + a8*gz + c2 + 1.f)*32.5f;
    int xf=(int)floorf(px), yf=(int)floorf(py), zf=(int)floorf(pz);
    int x0=min(max(xf,0),65), x1=min(max(xf+1,0),65);
    int y0=min(max(yf,0),65), y1=min(max(yf+1,0),65);
    int z0=min(max(zf,0),65), z1=min(max(zf+1,0),65);
    float dx=px-(float)x0, dy=py-(float)y0, dz=pz-(float)z0;
    float ex=1.f-dx, ey=1.f-dy, ez=1.f-dz;
    int lx0=min(max(x0-sx0,0),15), lx1=min(max(x1-sx0,0),15);
    int ly0=min(max(y0-sy0,0),15), ly1=min(max(y1-sy0,0),15);
    int lz0=min(max(z0-sz0,0),15), lz1=min(max(z1-sz0,0),15);
    int xA=lx0*272, xB=lx1*272, yA=ly0*17, yB=ly1*17;
    float rv = ex*ey*ez*sX[xA+yA+lz0] + ex*ey*dz*sX[xA+yA+lz1]
             + ex*dy*ez*sX[xA+yB+lz0] + ex*dy*dz*sX[xA+yB+lz1]
             + dx*ey*ez*sX[xB+yA+lz0] + dx*ey*dz*sX[xB+yA+lz1]
             + dx*dy*ez*sX[xB+yB+lz0] + dx*dy*dz*sX[xB+yB+lz1];
    size_t oi = (size_t)batch*NNN + ((size_t)(ox+xo)<<12) + ((oy+yo)<<6) + (oz+zo);
    Xt[oi] = rv;
  }
}

// ---------------- forward slab: FFT over y then z for one (b,x) slab --------
__global__ __launch_bounds__(64,1) void k_fwd_slab(const float* __restrict__ src, float2* __restrict__ dst){
  __shared__ float re[64*65];
  __shared__ float im[64*65];
  int s = blockIdx.x;
  int t = threadIdx.x;
  const float* p = src + (size_t)s*NN;
  float2 v[64];
  #pragma unroll
  for(int y=0;y<64;y++) v[y] = make_float2(p[y*64+t], 0.f);
  fft64<-1>(v);
  #pragma unroll
  for(int i=0;i<64;i++){ float2 q = v[PERMI(i)]; re[i*65+t]=q.x; im[i*65+t]=q.y; }
  __syncthreads();
  #pragma unroll
  for(int z=0;z<64;z++) v[z] = make_float2(re[t*65+z], im[t*65+z]);
  fft64<-1>(v);
  #pragma unroll
  for(int i=0;i<64;i++){ float2 q = v[PERMI(i)]; re[t*65+i]=q.x; im[t*65+i]=q.y; }
  __syncthreads();
  float2* d = dst + (size_t)s*NN;
  #pragma unroll
  for(int i=0;i<64;i++) d[i*64+t] = make_float2(re[i*65+t], im[i*65+t]);
}

// ------- conv along x: FFT-x, multiply by shifted mask, iFFT-x, in place ----
// __launch_bounds__(256,1): NO vgpr cap — round-2's (256,2) forced 128 VGPRs
// and spilled ~150MB of scratch per dispatch (WRITE_SIZE 217MB vs 67 ideal).
__global__ __launch_bounds__(256,1) void k_conv_x(float2* __restrict__ A, const float* __restrict__ M){
  int lid = blockIdx.x*blockDim.x + threadIdx.x;
  int z = lid & 63, y = (lid>>6) & 63, b = lid>>12;
  float2* p = A + (size_t)b*NNN + y*64 + z;
  const float* m = M + (size_t)b*NNN + ((y^32)<<6) + (z^32);
  float2 v[64];
  #pragma unroll
  for(int k=0;k<64;k++) v[k] = p[(size_t)k*NN];
  fft64<-1>(v);
  #pragma unroll
  for(int i=0;i<64;i++){
    float mm = m[(size_t)(i^32)*NN];
    v[PERMI(i)].x *= mm;
    v[PERMI(i)].y *= mm;
  }
  fft64_pin_nat<1>(v);
  #pragma unroll
  for(int i=0;i<64;i++) p[(size_t)i*NN] = v[i];
}

// -------- inverse slab: iFFT over y then z, scale, take real, write/acc -----
template<bool ACC>
__global__ __launch_bounds__(64,1) void k_inv_slab(const float2* __restrict__ src, float* __restrict__ dst){
  __shared__ float re[64*65];
  __shared__ float im[64*65];
  int s = blockIdx.x;
  int t = threadIdx.x;
  const float2* p = src + (size_t)s*NN;
  float2 v[64];
  #pragma unroll
  for(int ky=0;ky<64;ky++) v[ky] = p[ky*64+t];
  fft64<1>(v);
  #pragma unroll
  for(int i=0;i<64;i++){ float2 q = v[PERMI(i)]; re[i*65+t]=q.x; im[i*65+t]=q.y; }
  __syncthreads();
  #pragma unroll
  for(int kz=0;kz<64;kz++) v[kz] = make_float2(re[t*65+kz], im[t*65+kz]);
  fft64<1>(v);
  const float scl = 1.0f/262144.0f;
  #pragma unroll
  for(int i=0;i<64;i++) re[t*65+i] = v[PERMI(i)].x * scl;
  __syncthreads();
  float* d = dst + (size_t)s*NN;
  #pragma unroll
  for(int i=0;i<64;i++){
    float val = re[i*65+t];
    if (ACC) d[i*64+t] += val; else d[i*64+t] = val;
  }
}

extern "C" void kernel_launch(void* const* d_in, const int* in_sizes, int n_in,
                              void* d_out, int out_size, void* d_ws, size_t ws_size,
                              hipStream_t stream){
  const float* X  = (const float*)d_in[0];
  const float* Y  = (const float*)d_in[1];
  const float* m1 = (const float*)d_in[2];
  const float* m2 = (const float*)d_in[3];
  const float* th = (const float*)d_in[4];
  float* out0 = (float*)d_out;
  float* out1 = out0 + (size_t)NB*NNN;
  float* out2 = out1 + (size_t)NB*NNN;
  float2* A  = (float2*)d_ws;
  float*  aff = (float*)((char*)d_ws + (size_t)NB*NNN*sizeof(float2));

  k_affine<<<dim3(1), dim3(32), 0, stream>>>(th, aff);
  k_warp_masks<<<dim3(NB*512), dim3(256), 0, stream>>>(m1, m2, aff, out1, out2);
  k_warp_x<<<dim3(NB*512), dim3(256), 0, stream>>>(X, aff, out0);

  k_fwd_slab<<<dim3(NB*64), dim3(64), 0, stream>>>(out0, A);
  k_conv_x<<<dim3(NB*NN/256), dim3(256), 0, stream>>>(A, out1);
  k_inv_slab<false><<<dim3(NB*64), dim3(64), 0, stream>>>(A, out0);

  k_fwd_slab<<<dim3(NB*64), dim3(64), 0, stream>>>(Y, A);
  k_conv_x<<<dim3(NB*NN/256), dim3(256), 0, stream>>>(A, out2);
  k_inv_slab<true><<<dim3(NB*64), dim3(64), 0, stream>>>(A, out0);
}

// Round 4
// 422.484 us; speedup vs baseline: 1.5505x; 1.1085x over previous
//
#include <hip/hip_runtime.h>
#include <hip/hip_fp16.h>
#include <math.h>

#define NB 32
#define NN 4096      // 64*64
#define NNN 262144   // 64^3
#define PERMI(i) ((((i)&7)<<3)|((i)>>3))

__device__ __forceinline__ float2 cadd(float2 a, float2 b){ return make_float2(a.x+b.x, a.y+b.y); }
__device__ __forceinline__ float2 csub(float2 a, float2 b){ return make_float2(a.x-b.x, a.y-b.y); }
__device__ __forceinline__ float2 cmulc(float2 a, float2 b){ return make_float2(a.x*b.x - a.y*b.y, a.x*b.y + a.y*b.x); }
template<int S> __device__ __forceinline__ float2 cmuli(float2 a){
  return (S>0)? make_float2(-a.y,a.x) : make_float2(a.y,-a.x);
}

template<int S>
__device__ __forceinline__ void dft8(float2* a){
  const float r_ = 0.70710678118654752f;
  float2 t0=cadd(a[0],a[4]), t1=csub(a[0],a[4]);
  float2 t2=cadd(a[2],a[6]), t3=csub(a[2],a[6]);
  float2 u0=cadd(a[1],a[5]), u1=csub(a[1],a[5]);
  float2 u2=cadd(a[3],a[7]), u3=csub(a[3],a[7]);
  float2 E0=cadd(t0,t2), E2=csub(t0,t2);
  float2 it3=cmuli<S>(t3);
  float2 E1=cadd(t1,it3), E3=csub(t1,it3);
  float2 O0=cadd(u0,u2), O2=csub(u0,u2);
  float2 iu3=cmuli<S>(u3);
  float2 O1=cadd(u1,iu3), O3=csub(u1,iu3);
  const float sr = (S>0)? r_ : -r_;
  float2 W1 = make_float2(r_, sr);
  float2 W3 = make_float2(-r_, sr);
  float2 o1 = cmulc(O1,W1);
  float2 o2 = cmuli<S>(O2);
  float2 o3 = cmulc(O3,W3);
  a[0]=cadd(E0,O0); a[4]=csub(E0,O0);
  a[1]=cadd(E1,o1); a[5]=csub(E1,o1);
  a[2]=cadd(E2,o2); a[6]=csub(E2,o2);
  a[3]=cadd(E3,o3); a[7]=csub(E3,o3);
}

#define TWTAB \
  const float TWC[8]={1.f,0.9951847266721969f,0.9807852804032304f,0.9569403357322088f, \
                      0.9238795325112867f,0.8819212643483551f,0.8314696123025452f,0.7730104533627370f}; \
  const float TWS[8]={0.f,0.0980171403295606f,0.1950903220161283f,0.2902846772544624f, \
                      0.3826834323650898f,0.4713967368259976f,0.5555702330196022f,0.6343932841636455f};

// natural input -> logical i at v[PERMI(i)], in-place
template<int S>
__device__ __forceinline__ void fft64(float2* v){
  #pragma unroll
  for(int n2=0;n2<8;n2++){
    float2 t[8];
    #pragma unroll
    for(int n1=0;n1<8;n1++) t[n1] = v[8*n1+n2];
    dft8<S>(t);
    #pragma unroll
    for(int k1=0;k1<8;k1++) v[8*k1+n2] = t[k1];
  }
  TWTAB
  #pragma unroll
  for(int k1=1;k1<8;k1++){
    float2 wb = make_float2(TWC[k1], (S>0)? TWS[k1] : -TWS[k1]);
    float2 w = wb;
    #pragma unroll
    for(int n2=1;n2<8;n2++){
      v[8*k1+n2] = cmulc(v[8*k1+n2], w);
      w = cmulc(w, wb);
    }
  }
  #pragma unroll
  for(int k1=0;k1<8;k1++){
    float2 t[8];
    #pragma unroll
    for(int n2=0;n2<8;n2++) t[n2]=v[8*k1+n2];
    dft8<S>(t);
    #pragma unroll
    for(int k2=0;k2<8;k2++) v[8*k1+k2]=t[k2];
  }
}

// PERM-placed input -> natural output, in-place
template<int S>
__device__ __forceinline__ void fft64_pin_nat(float2* v){
  #pragma unroll
  for(int r=0;r<8;r++){
    float2 t[8];
    #pragma unroll
    for(int a=0;a<8;a++) t[a]=v[8*r+a];
    dft8<S>(t);
    #pragma unroll
    for(int q=0;q<8;q++) v[8*r+q]=t[q];
  }
  TWTAB
  #pragma unroll
  for(int r=1;r<8;r++){
    float2 wb = make_float2(TWC[r], (S>0)? TWS[r] : -TWS[r]);
    float2 w = wb;
    #pragma unroll
    for(int q=1;q<8;q++){
      v[8*r+q] = cmulc(v[8*r+q], w);
      w = cmulc(w, wb);
    }
  }
  #pragma unroll
  for(int q=0;q<8;q++){
    float2 t[8];
    #pragma unroll
    for(int b=0;b<8;b++) t[b]=v[8*b+q];
    dft8<S>(t);
    #pragma unroll
    for(int m=0;m<8;m++) v[8*m+q]=t[m];
  }
}

__device__ __forceinline__ float2 h2f(__half2 h){ return __half22float2(h); }
__device__ __forceinline__ __half2 f2h(float2 f){ return __floats2half2_rn(f.x, f.y); }

// ---------------- affine params ----------------
__global__ void k_affine(const float* __restrict__ theta, float* __restrict__ aff){
  int b = threadIdx.x;
  if(b >= NB) return;
  const float* t = theta + b*6;
  const float PIf = 3.14159265358979323846f;
  float phi = t[0]*(2.f*PIf) - PIf;
  float th  = t[1]*(2.f*PIf) - PIf;
  float psi = t[2]*(2.f*PIf) - PIf;
  float cph = cosf(phi), sph = sinf(phi);
  float cth = cosf(th),  sth = sinf(th);
  float cps = cosf(psi), sps = sinf(psi);
  float R00 = cph*cth*cps - sph*sps;
  float R01 = -cph*cth*sps - sph*cps;
  float R02 = cph*sth;
  float R10 = sph*cth*cps + cph*sps;
  float R11 = -sph*cth*sps + cph*cps;
  float R12 = sph*sth;
  float R20 = -sth*cps;
  float R21 = sth*sps;
  float R22 = cth;
  float rm0=R00, rm1=R10, rm2=R20;
  float rm3=R01, rm4=R11, rm5=R21;
  float rm6=R02, rm7=R12, rm8=R22;
  float* o = aff + b*16;
  o[0]=rm0; o[1]=rm1; o[2]=rm2;
  o[3]=rm3; o[4]=rm4; o[5]=rm5;
  o[6]=rm6; o[7]=rm7; o[8]=rm8;
  const float sc = 64.0f/66.0f;
  float lx = (2.f*t[3]-1.f)*sc;
  float ly = (2.f*t[4]-1.f)*sc;
  float lz = (2.f*t[5]-1.f)*sc;
  o[9]  = -(rm0*lx + rm1*ly + rm2*lz);
  o[10] = -(rm3*lx + rm4*ly + rm5*lz);
  o[11] = -(rm6*lx + rm7*ly + rm8*lz);
}

// block/tile decode with XCD pinning
__device__ __forceinline__ void tile_decode(int blk, int& batch, int& ox, int& oy, int& oz){
  int xcd = blk & 7;
  int j = blk >> 3;
  batch = xcd + ((j >> 9) << 3);
  int tile = j & 511;
  oz = (tile & 7) << 3;
  oy = ((tile >> 3) & 7) << 3;
  ox = (tile >> 6) << 3;
}

#define LDSI(xi,yi,zi) ((((xi)*16)+(yi))*17+(zi))

// ---------------- mask warp: half2-packed LDS-staged tiled gather -----------
__global__ __launch_bounds__(256) void k_warp_masks(const float* __restrict__ m1, const float* __restrict__ m2,
                             const float* __restrict__ aff,
                             float* __restrict__ M1, float* __restrict__ M2){
  __shared__ __half2 s12[16*16*17];    // lo=m1, hi=m2 — 17.4 KB, 8 blocks/CU
  int batch, ox, oy, oz;
  tile_decode(blockIdx.x, batch, ox, oy, oz);
  const float* a = aff + batch*16;
  float a0=a[0],a1=a[1],a2=a[2],a3=a[3],a4=a[4],a5=a[5],a6=a[6],a7=a[7],a8=a[8];

  float gxl = ox*(2.f/63.f)-1.f, gxh = (ox+7)*(2.f/63.f)-1.f;
  float gyl = oy*(2.f/63.f)-1.f, gyh = (oy+7)*(2.f/63.f)-1.f;
  float gzl = oz*(2.f/63.f)-1.f, gzh = (oz+7)*(2.f/63.f)-1.f;
  #define MM(c,lo,hi) fminf((c)*(lo),(c)*(hi))
  float minx = (1.f + MM(a0,gxl,gxh) + MM(a1,gyl,gyh) + MM(a2,gzl,gzh))*31.5f;
  float miny = (1.f + MM(a3,gxl,gxh) + MM(a4,gyl,gyh) + MM(a5,gzl,gzh))*31.5f;
  float minz = (1.f + MM(a6,gxl,gxh) + MM(a7,gyl,gyh) + MM(a8,gzl,gzh))*31.5f;
  #undef MM
  int sx0 = min(max((int)floorf(minx-0.01f),0),48);
  int sy0 = min(max((int)floorf(miny-0.01f),0),48);
  int sz0 = min(max((int)floorf(minz-0.01f),0),48);

  {
    int zi = threadIdx.x & 15, yi = threadIdx.x >> 4;
    const float* p1 = m1 + (size_t)batch*NNN + ((sy0+yi)<<6) + (sz0+zi);
    const float* p2 = m2 + (size_t)batch*NNN + ((sy0+yi)<<6) + (sz0+zi);
    #pragma unroll
    for(int xi=0;xi<16;xi++){
      float f1 = p1[(size_t)(sx0+xi)<<12];
      float f2 = p2[(size_t)(sx0+xi)<<12];
      s12[LDSI(xi,yi,zi)] = __floats2half2_rn(f1, f2);
    }
  }
  __syncthreads();

  #pragma unroll
  for(int o=0;o<2;o++){
    int v = threadIdx.x + o*256;
    int zo = v & 7, yo = (v>>3)&7, xo = v>>6;
    float gx = (ox+xo)*(2.f/63.f)-1.f;
    float gy = (oy+yo)*(2.f/63.f)-1.f;
    float gz = (oz+zo)*(2.f/63.f)-1.f;
    float px = (a0*gx + a1*gy + a2*gz + 1.f)*31.5f;
    float py = (a3*gx + a4*gy + a5*gz + 1.f)*31.5f;
    float pz = (a6*gx + a7*gy + a8*gz + 1.f)*31.5f;
    int xf=(int)floorf(px), yf=(int)floorf(py), zf=(int)floorf(pz);
    int x0=min(max(xf,0),63), x1=min(max(xf+1,0),63);
    int y0=min(max(yf,0),63), y1=min(max(yf+1,0),63);
    int z0=min(max(zf,0),63), z1=min(max(zf+1,0),63);
    float dx=px-(float)x0, dy=py-(float)y0, dz=pz-(float)z0;
    float ex=1.f-dx, ey=1.f-dy, ez=1.f-dz;
    int lx0=min(max(x0-sx0,0),15), lx1=min(max(x1-sx0,0),15);
    int ly0=min(max(y0-sy0,0),15), ly1=min(max(y1-sy0,0),15);
    int lz0=min(max(z0-sz0,0),15), lz1=min(max(z1-sz0,0),15);
    int xA=lx0*272, xB=lx1*272, yA=ly0*17, yB=ly1*17;
    float2 c000=h2f(s12[xA+yA+lz0]), c001=h2f(s12[xA+yA+lz1]);
    float2 c010=h2f(s12[xA+yB+lz0]), c011=h2f(s12[xA+yB+lz1]);
    float2 c100=h2f(s12[xB+yA+lz0]), c101=h2f(s12[xB+yA+lz1]);
    float2 c110=h2f(s12[xB+yB+lz0]), c111=h2f(s12[xB+yB+lz1]);
    float w000=ex*ey*ez, w001=ex*ey*dz, w010=ex*dy*ez, w011=ex*dy*dz;
    float w100=dx*ey*ez, w101=dx*ey*dz, w110=dx*dy*ez, w111=dx*dy*dz;
    float r1 = w000*c000.x+w001*c001.x+w010*c010.x+w011*c011.x
             + w100*c100.x+w101*c101.x+w110*c110.x+w111*c111.x;
    float r2 = w000*c000.y+w001*c001.y+w010*c010.y+w011*c011.y
             + w100*c100.y+w101*c101.y+w110*c110.y+w111*c111.y;
    size_t oi = (size_t)batch*NNN + ((size_t)(ox+xo)<<12) + ((oy+yo)<<6) + (oz+zo);
    M1[oi] = r1;
    M2[oi] = r2;
  }
}

// ---------------- X warp: LDS-staged tiled gather over padded-66 space -------
__global__ __launch_bounds__(256) void k_warp_x(const float* __restrict__ X, const float* __restrict__ aff,
                         float* __restrict__ Xt){
  __shared__ float sX[16*16*17];
  int batch, ox, oy, oz;
  tile_decode(blockIdx.x, batch, ox, oy, oz);
  const float* a = aff + batch*16;
  float a0=a[0],a1=a[1],a2=a[2],a3=a[3],a4=a[4],a5=a[5],a6=a[6],a7=a[7],a8=a[8];
  float c0=a[9], c1=a[10], c2=a[11];

  float gxl = (ox+1)*(2.f/65.f)-1.f, gxh = (ox+8)*(2.f/65.f)-1.f;
  float gyl = (oy+1)*(2.f/65.f)-1.f, gyh = (oy+8)*(2.f/65.f)-1.f;
  float gzl = (oz+1)*(2.f/65.f)-1.f, gzh = (oz+8)*(2.f/65.f)-1.f;
  #define MM(c,lo,hi) fminf((c)*(lo),(c)*(hi))
  float minx = (MM(a0,gxl,gxh) + MM(a1,gyl,gyh) + MM(a2,gzl,gzh) + c0 + 1.f)*32.5f;
  float miny = (MM(a3,gxl,gxh) + MM(a4,gyl,gyh) + MM(a5,gzl,gzh) + c1 + 1.f)*32.5f;
  float minz = (MM(a6,gxl,gxh) + MM(a7,gyl,gyh) + MM(a8,gzl,gzh) + c2 + 1.f)*32.5f;
  #undef MM
  int sx0 = min(max((int)floorf(minx-0.01f),0),50);
  int sy0 = min(max((int)floorf(miny-0.01f),0),50);
  int sz0 = min(max((int)floorf(minz-0.01f),0),50);

  {
    int zi = threadIdx.x & 15, yi = threadIdx.x >> 4;
    int ys = sy0 + yi, zs = sz0 + zi;
    bool yz_ok = ((unsigned)(ys-1) < 64u) && ((unsigned)(zs-1) < 64u);
    const float* p = X + (size_t)batch*NNN + ((ys-1)<<6) + (zs-1);
    #pragma unroll
    for(int xi=0;xi<16;xi++){
      int xs = sx0 + xi;
      float val = (yz_ok && ((unsigned)(xs-1) < 64u)) ? p[(size_t)(xs-1)<<12] : 0.f;
      sX[LDSI(xi,yi,zi)] = val;
    }
  }
  __syncthreads();

  #pragma unroll
  for(int o=0;o<2;o++){
    int v = threadIdx.x + o*256;
    int zo = v & 7, yo = (v>>3)&7, xo = v>>6;
    float gx = (ox+xo+1)*(2.f/65.f)-1.f;
    float gy = (oy+yo+1)*(2.f/65.f)-1.f;
    float gz = (oz+zo+1)*(2.f/65.f)-1.f;
    float px = (a0*gx + a1*gy + a2*gz + c0 + 1.f)*32.5f;
    float py = (a3*gx + a4*gy + a5*gz + c1 + 1.f)*32.5f;
    float pz = (a6*gx + a7*gy + a8*gz + c2 + 1.f)*32.5f;
    int xf=(int)floorf(px), yf=(int)floorf(py), zf=(int)floorf(pz);
    int x0=min(max(xf,0),65), x1=min(max(xf+1,0),65);
    int y0=min(max(yf,0),65), y1=min(max(yf+1,0),65);
    int z0=min(max(zf,0),65), z1=min(max(zf+1,0),65);
    float dx=px-(float)x0, dy=py-(float)y0, dz=pz-(float)z0;
    float ex=1.f-dx, ey=1.f-dy, ez=1.f-dz;
    int lx0=min(max(x0-sx0,0),15), lx1=min(max(x1-sx0,0),15);
    int ly0=min(max(y0-sy0,0),15), ly1=min(max(y1-sy0,0),15);
    int lz0=min(max(z0-sz0,0),15), lz1=min(max(z1-sz0,0),15);
    int xA=lx0*272, xB=lx1*272, yA=ly0*17, yB=ly1*17;
    float rv = ex*ey*ez*sX[xA+yA+lz0] + ex*ey*dz*sX[xA+yA+lz1]
             + ex*dy*ez*sX[xA+yB+lz0] + ex*dy*dz*sX[xA+yB+lz1]
             + dx*ey*ez*sX[xB+yA+lz0] + dx*ey*dz*sX[xB+yA+lz1]
             + dx*dy*ez*sX[xB+yB+lz0] + dx*dy*dz*sX[xB+yB+lz1];
    size_t oi = (size_t)batch*NNN + ((size_t)(ox+xo)<<12) + ((oy+yo)<<6) + (oz+zo);
    Xt[oi] = rv;
  }
}

// ------- forward slab: FFT over y then z, fp16-complex LDS + output ---------
__global__ __launch_bounds__(64,1) void k_fwd_slab(const float* __restrict__ src, __half2* __restrict__ dst){
  __shared__ __half2 sh[64*65];    // 16.6 KB -> 8 blocks/CU
  int s = blockIdx.x;
  int t = threadIdx.x;
  const float* p = src + (size_t)s*NN;
  float2 v[64];
  #pragma unroll
  for(int y=0;y<64;y++) v[y] = make_float2(p[y*64+t], 0.f);
  fft64<-1>(v);
  #pragma unroll
  for(int i=0;i<64;i++) sh[i*65+t] = f2h(v[PERMI(i)]);
  __syncthreads();
  #pragma unroll
  for(int z=0;z<64;z++) v[z] = h2f(sh[t*65+z]);
  fft64<-1>(v);
  __syncthreads();
  #pragma unroll
  for(int i=0;i<64;i++) sh[t*65+i] = f2h(v[PERMI(i)]);
  __syncthreads();
  __half2* d = dst + (size_t)s*NN;
  #pragma unroll
  for(int i=0;i<64;i++) d[i*64+t] = sh[i*65+t];
}

// ------- conv along x: FFT-x, * shifted mask * (1/64), iFFT-x, in place -----
__global__ __launch_bounds__(256,1) void k_conv_x(__half2* __restrict__ A, const float* __restrict__ M){
  int lid = blockIdx.x*blockDim.x + threadIdx.x;
  int z = lid & 63, y = (lid>>6) & 63, b = lid>>12;
  __half2* p = A + (size_t)b*NNN + y*64 + z;
  const float* m = M + (size_t)b*NNN + ((y^32)<<6) + (z^32);
  float2 v[64];
  #pragma unroll
  for(int k=0;k<64;k++) v[k] = h2f(p[(size_t)k*NN]);
  fft64<-1>(v);
  #pragma unroll
  for(int i=0;i<64;i++){
    float mm = m[(size_t)(i^32)*NN] * 0.015625f;   // fold 1/64 of ifft norm (fp16 range guard)
    v[PERMI(i)].x *= mm;
    v[PERMI(i)].y *= mm;
  }
  fft64_pin_nat<1>(v);
  #pragma unroll
  for(int i=0;i<64;i++) p[(size_t)i*NN] = f2h(v[i]);
}

// -- inverse slab on A+B sum: iFFT y,z once, scale, real part, write out0 ----
__global__ __launch_bounds__(64,1) void k_inv_sum(const __half2* __restrict__ a,
                                                  const __half2* __restrict__ bb,
                                                  float* __restrict__ dst){
  __shared__ float sre[64*65];     // 16.6 KB; phase-1 aliases it as __half2
  __half2* shh = (__half2*)sre;
  int s = blockIdx.x;
  int t = threadIdx.x;
  const __half2* pa = a  + (size_t)s*NN;
  const __half2* pb = bb + (size_t)s*NN;
  float2 v[64];
  #pragma unroll
  for(int ky=0;ky<64;ky++){
    float2 fa = h2f(pa[ky*64+t]);
    float2 fb = h2f(pb[ky*64+t]);
    v[ky] = cadd(fa, fb);
  }
  fft64<1>(v);
  #pragma unroll
  for(int i=0;i<64;i++) shh[i*65+t] = f2h(v[PERMI(i)]);
  __syncthreads();
  #pragma unroll
  for(int kz=0;kz<64;kz++) v[kz] = h2f(shh[t*65+kz]);
  __syncthreads();                 // done reading half2 view before float reuse
  fft64<1>(v);
  const float scl = 1.0f/4096.0f;  // remaining ifft norm (1/64 folded into conv)
  #pragma unroll
  for(int i=0;i<64;i++) sre[t*65+i] = v[PERMI(i)].x * scl;
  __syncthreads();
  float* d = dst + (size_t)s*NN;
  #pragma unroll
  for(int i=0;i<64;i++) d[i*64+t] = sre[i*65+t];
}

extern "C" void kernel_launch(void* const* d_in, const int* in_sizes, int n_in,
                              void* d_out, int out_size, void* d_ws, size_t ws_size,
                              hipStream_t stream){
  const float* X  = (const float*)d_in[0];
  const float* Y  = (const float*)d_in[1];
  const float* m1 = (const float*)d_in[2];
  const float* m2 = (const float*)d_in[3];
  const float* th = (const float*)d_in[4];
  float* out0 = (float*)d_out;
  float* out1 = out0 + (size_t)NB*NNN;
  float* out2 = out1 + (size_t)NB*NNN;
  __half2* A = (__half2*)d_ws;                       // 32 MB fp16-complex (X pipeline)
  __half2* B = A + (size_t)NB*NNN;                   // 32 MB fp16-complex (Y pipeline)
  float*  aff = (float*)((char*)d_ws + 2*(size_t)NB*NNN*sizeof(__half2));

  k_affine<<<dim3(1), dim3(32), 0, stream>>>(th, aff);
  k_warp_masks<<<dim3(NB*512), dim3(256), 0, stream>>>(m1, m2, aff, out1, out2);
  k_warp_x<<<dim3(NB*512), dim3(256), 0, stream>>>(X, aff, out0);

  k_fwd_slab<<<dim3(NB*64), dim3(64), 0, stream>>>(out0, A);
  k_conv_x<<<dim3(NB*NN/256), dim3(256), 0, stream>>>(A, out1);
  k_fwd_slab<<<dim3(NB*64), dim3(64), 0, stream>>>(Y, B);
  k_conv_x<<<dim3(NB*NN/256), dim3(256), 0, stream>>>(B, out2);
  k_inv_sum<<<dim3(NB*64), dim3(64), 0, stream>>>(A, B, out0);
}